// Round 1
// baseline (603.566 us; speedup 1.0000x reference)
//
#include <hip/hip_runtime.h>
#include <math.h>

#define NN 50000
#define NE 640000
#define NR 8
#define SCAN_N (NN * NR)  // 400000 segments
#define SCAN_CH 2048      // elements per scan block
#define SCAN_NB ((SCAN_N + SCAN_CH - 1) / SCAN_CH)  // 196

typedef __attribute__((ext_vector_type(8))) _Float16 half8;
typedef __attribute__((ext_vector_type(8))) short short8;
typedef __attribute__((ext_vector_type(4))) float f32x4;

__device__ __forceinline__ unsigned short f2h(float f) {
    _Float16 h = (_Float16)f;                       // v_cvt_f16_f32, RNE
    return __builtin_bit_cast(unsigned short, h);
}
__device__ __forceinline__ float h2f(unsigned short u) {
    return (float)__builtin_bit_cast(_Float16, u);
}

// ---------- preprocessing ----------
__global__ __launch_bounds__(256) void count_kernel(const int* __restrict__ dst,
                                                    const int* __restrict__ typ,
                                                    int* __restrict__ cnt, int E) {
    int e = blockIdx.x * 256 + threadIdx.x;
    if (e < E) atomicAdd(&cnt[dst[e] * NR + typ[e]], 1);
}

__global__ __launch_bounds__(256) void inv_kernel(const int* __restrict__ cnt,
                                                  float* __restrict__ inv, int n) {
    int i = blockIdx.x * 256 + threadIdx.x;
    if (i < n) {
        int c = cnt[i];
        inv[i] = 1.0f / (float)(c > 1 ? c : 1);
    }
}

// ---- hierarchical scan
__global__ __launch_bounds__(256) void scan1_kernel(const int* __restrict__ cnt,
                                                    int* __restrict__ loc,
                                                    int* __restrict__ bsum) {
    __shared__ int s[256];
    const int t = threadIdx.x;
    const int base = blockIdx.x * SCAN_CH + t * 8;
    int v[8];
    int sum = 0;
#pragma unroll
    for (int j = 0; j < 8; ++j) {
        int idx = base + j;
        v[j] = (idx < SCAN_N) ? cnt[idx] : 0;
        sum += v[j];
    }
    s[t] = sum;
    __syncthreads();
    for (int off = 1; off < 256; off <<= 1) {
        int u = (t >= off) ? s[t - off] : 0;
        __syncthreads();
        s[t] += u;
        __syncthreads();
    }
    int run = (t == 0) ? 0 : s[t - 1];
#pragma unroll
    for (int j = 0; j < 8; ++j) {
        int idx = base + j;
        if (idx < SCAN_N) loc[idx] = run;
        run += v[j];
    }
    if (t == 255) bsum[blockIdx.x] = s[255];
}

__global__ __launch_bounds__(256) void scan2_kernel(const int* __restrict__ bsum,
                                                    int* __restrict__ boff, int nb) {
    __shared__ int s[256];
    const int t = threadIdx.x;
    s[t] = (t < nb) ? bsum[t] : 0;
    __syncthreads();
    for (int off = 1; off < 256; off <<= 1) {
        int u = (t >= off) ? s[t - off] : 0;
        __syncthreads();
        s[t] += u;
        __syncthreads();
    }
    if (t < nb) boff[t] = (t == 0) ? 0 : s[t - 1];
    if (t == nb - 1) boff[nb] = s[t];
}

__global__ __launch_bounds__(256) void scan3_kernel(int* __restrict__ rowptr,
                                                    int* __restrict__ start,
                                                    const int* __restrict__ boff, int nb) {
    const int b = blockIdx.x, t = threadIdx.x;
    const int add = boff[b];
#pragma unroll
    for (int j = 0; j < 8; ++j) {
        int idx = b * SCAN_CH + t * 8 + j;
        if (idx < SCAN_N) {
            int v = rowptr[idx] + add;
            rowptr[idx] = v;
            start[idx] = v;
        }
    }
    if (b == 0 && t == 0) rowptr[SCAN_N] = boff[nb];
}

// counting-sort by (dst,rel): srcrel[pos] = src | rel<<20
__global__ __launch_bounds__(256) void fill_kernel(const int* __restrict__ src,
                                                   const int* __restrict__ dst,
                                                   const int* __restrict__ typ,
                                                   int* __restrict__ start,
                                                   int* __restrict__ srcrel, int E) {
    int e = blockIdx.x * 256 + threadIdx.x;
    if (e >= E) return;
    int r = typ[e];
    int pos = atomicAdd(&start[dst[e] * NR + r], 1);
    srcrel[pos] = src[e] | (r << 20);
}

// ---------- x (fp32, [NN,128]) -> xh (fp16) ----------
__global__ __launch_bounds__(256) void cvt_kernel(const float* __restrict__ x,
                                                  unsigned short* __restrict__ xh, int n4) {
    int i = blockIdx.x * 256 + threadIdx.x;
    if (i >= n4) return;
    float4 v = ((const float4*)x)[i];
    uint2 u;
    u.x = (unsigned)f2h(v.x) | ((unsigned)f2h(v.y) << 16);
    u.y = (unsigned)f2h(v.z) | ((unsigned)f2h(v.w) << 16);
    ((uint2*)xh)[i] = u;
}

// ---------- weight pack: Bt[n][k] fp16, n in [0,9*O): n<8*O -> W[r=n/O][k][o=n%O], else root[k][n-8*O]
__global__ __launch_bounds__(256) void pack_b_kernel(const float* __restrict__ W,
                                                     const float* __restrict__ root,
                                                     unsigned short* __restrict__ Bt, int O) {
    int i = blockIdx.x * 256 + threadIdx.x;
    int NTOT = 9 * O;
    if (i >= NTOT * 128) return;
    int k = i & 127, n = i >> 7;
    float v = (n < 8 * O) ? W[(size_t)(n / O) * 128 * O + (size_t)k * O + (n % O)]
                          : root[(size_t)k * O + (n - 8 * O)];
    Bt[(size_t)n * 128 + k] = f2h(v);
}

// ---------- fused aggregate-first RGCN layer ----------
// h[dst] = sum_r (mean_{src in N_r(dst)} X[src]) @ W_r + X[dst] @ root + b   (+ sigmoid)
// Block: 32 dst, 4 waves. Phase 1: per-wave gather+mean of raw features into
// LDS tile A[32][8*128] fp16 (XOR-swizzled). Phase 2: 32xO GEMM, K = 9*128
// (root streamed from global), MFMA 16x16x32 f16, bias/sigmoid epilogue.
#define ACC_EDGE(P, G)                                                        \
    do {                                                                      \
        unsigned r_ = ((unsigned)(P)) >> 20;                                  \
        float vx_ = h2f((unsigned short)((G) & 0xFFFFu));                     \
        float vy_ = h2f((unsigned short)((G) >> 16));                         \
        switch (r_) {                                                         \
            case 0: acc[0].x += vx_; acc[0].y += vy_; break;                  \
            case 1: acc[1].x += vx_; acc[1].y += vy_; break;                  \
            case 2: acc[2].x += vx_; acc[2].y += vy_; break;                  \
            case 3: acc[3].x += vx_; acc[3].y += vy_; break;                  \
            case 4: acc[4].x += vx_; acc[4].y += vy_; break;                  \
            case 5: acc[5].x += vx_; acc[5].y += vy_; break;                  \
            case 6: acc[6].x += vx_; acc[6].y += vy_; break;                  \
            default: acc[7].x += vx_; acc[7].y += vy_; break;                 \
        }                                                                     \
    } while (0)

template <int O, bool FINAL>
__global__ __launch_bounds__(256, 2) void fused_layer(
    const int* __restrict__ rp, const int* __restrict__ srcrel,
    const float* __restrict__ inv, const unsigned short* __restrict__ X,
    const unsigned short* __restrict__ Bt, const float* __restrict__ bias,
    void* __restrict__ Hout) {
    __shared__ __align__(16) unsigned short As[32 * 1024];  // 64 KB
    const int t = threadIdx.x;
    const int w = t >> 6, lane = t & 63;
    const int bm = blockIdx.x * 32;
    const unsigned* X2 = (const unsigned*)X;  // half2 view, row stride 64

    // ---- phase 1: aggregate 8 dst per wave ----
    for (int i = 0; i < 8; ++i) {
        const int m = w * 8 + i;  // local LDS row 0..31
        int d = bm + m;
        if (d >= NN) d = NN - 1;  // dup work, stores masked in epilogue
        float2 acc[8];
#pragma unroll
        for (int r = 0; r < 8; ++r) acc[r] = make_float2(0.f, 0.f);

        const int beg = rp[d * 8], end = rp[d * 8 + 8];
        for (int base = beg; base < end; base += 64) {
            int nv = end - base;
            nv = nv > 64 ? 64 : nv;
            int idx = base + (lane < nv ? lane : nv - 1);
            int pv = srcrel[idx];  // batched edge records, one per lane
            int j = 0;
            for (; j + 3 < nv; j += 4) {
                int p0 = __builtin_amdgcn_readlane(pv, j);
                int p1 = __builtin_amdgcn_readlane(pv, j + 1);
                int p2 = __builtin_amdgcn_readlane(pv, j + 2);
                int p3 = __builtin_amdgcn_readlane(pv, j + 3);
                unsigned g0 = X2[(p0 & 0xFFFFF) * 64 + lane];
                unsigned g1 = X2[(p1 & 0xFFFFF) * 64 + lane];
                unsigned g2 = X2[(p2 & 0xFFFFF) * 64 + lane];
                unsigned g3 = X2[(p3 & 0xFFFFF) * 64 + lane];
                ACC_EDGE(p0, g0);
                ACC_EDGE(p1, g1);
                ACC_EDGE(p2, g2);
                ACC_EDGE(p3, g3);
            }
            for (; j < nv; ++j) {
                int p0 = __builtin_amdgcn_readlane(pv, j);
                unsigned g0 = X2[(p0 & 0xFFFFF) * 64 + lane];
                ACC_EDGE(p0, g0);
            }
        }
        // scale by 1/cnt, fp16-pack, swizzled LDS store (bank-conflict-free)
        char* rowp = (char*)As + m * 2048;
        const int swz = (m & 7) << 4;
#pragma unroll
        for (int r = 0; r < 8; ++r) {
            float iv = inv[d * 8 + r];
            unsigned u = (unsigned)f2h(acc[r].x * iv) |
                         ((unsigned)f2h(acc[r].y * iv) << 16);
            *(unsigned*)(rowp + ((r * 256 + lane * 4) ^ swz)) = u;
        }
    }
    __syncthreads();

    // ---- phase 2: [32 x 9*128] @ Bt^T -> [32 x O] ----
    const int wr = w >> 1, wc = w & 1;
    const int q = lane >> 4, ml = lane & 15;
    constexpr int NT = O / 32;  // n-tiles per wave (cols wc*(O/2) .. +O/2)
    f32x4 accv[NT];
#pragma unroll
    for (int nt = 0; nt < NT; ++nt) accv[nt] = (f32x4)0.f;

    const int arow = wr * 16 + ml;
    int aglob = bm + arow;
    if (aglob >= NN) aglob = NN - 1;
    const unsigned short* Xroot = X + (size_t)aglob * 128;
    const char* arowp = (const char*)As + arow * 2048;
    const int aswz = (arow & 7) << 4;

#pragma unroll
    for (int r = 0; r < 9; ++r) {
#pragma unroll
        for (int kk = 0; kk < 4; ++kk) {
            half8 af;
            if (r < 8) {
                af = __builtin_bit_cast(
                    half8, *(const short8*)(arowp +
                                            ((r * 256 + kk * 64 + q * 16) ^ aswz)));
            } else {
                af = __builtin_bit_cast(half8,
                                        *(const short8*)(Xroot + kk * 32 + q * 8));
            }
#pragma unroll
            for (int nt = 0; nt < NT; ++nt) {
                const unsigned short* bp =
                    Bt + (size_t)(r * O + wc * (O / 2) + nt * 16 + ml) * 128 +
                    kk * 32 + q * 8;
                half8 bf = __builtin_bit_cast(half8, *(const short8*)bp);
                accv[nt] = __builtin_amdgcn_mfma_f32_16x16x32_f16(af, bf, accv[nt],
                                                                  0, 0, 0);
            }
        }
    }

    // epilogue: C/D layout col=lane&15, row=q*4+j
#pragma unroll
    for (int nt = 0; nt < NT; ++nt) {
        int col = wc * (O / 2) + nt * 16 + ml;
        float bv = bias[col];
#pragma unroll
        for (int j = 0; j < 4; ++j) {
            int grow = bm + wr * 16 + q * 4 + j;
            if (grow < NN) {
                float v = accv[nt][j] + bv;
                if (FINAL)
                    ((float*)Hout)[(size_t)grow * O + col] = 1.f / (1.f + __expf(-v));
                else
                    ((unsigned short*)Hout)[(size_t)grow * O + col] = f2h(v);
            }
        }
    }
}

extern "C" void kernel_launch(void* const* d_in, const int* in_sizes, int n_in,
                              void* d_out, int out_size, void* d_ws, size_t ws_size,
                              hipStream_t stream) {
    const float* x     = (const float*)d_in[0];
    const int*   esrc  = (const int*)d_in[1];
    const int*   edst  = (const int*)d_in[2];
    const int*   etyp  = (const int*)d_in[3];
    const float* W1    = (const float*)d_in[4];
    const float* root1 = (const float*)d_in[5];
    const float* b1    = (const float*)d_in[6];
    const float* W2    = (const float*)d_in[7];
    const float* root2 = (const float*)d_in[8];
    const float* b2    = (const float*)d_in[9];
    float* out = (float*)d_out;

    char* ws = (char*)d_ws;
    unsigned short* Bt1    = (unsigned short*)ws; ws += (size_t)1152 * 128 * 2; // 288 KB
    unsigned short* Bt2    = (unsigned short*)ws; ws += (size_t)576 * 128 * 2;  // 144 KB
    int*            cnt    = (int*)ws;            ws += (size_t)SCAN_N * 4;     // 1.6 MB
    float*          inv    = (float*)ws;          ws += (size_t)SCAN_N * 4;     // 1.6 MB
    int*            rp     = (int*)ws;            ws += (size_t)(SCAN_N + 64) * 4;
    int*            start  = (int*)ws;            ws += (size_t)SCAN_N * 4;     // 1.6 MB
    int*            bsum   = (int*)ws;            ws += (size_t)256 * 4;
    int*            boff   = (int*)ws;            ws += (size_t)257 * 4;
    int*            srcrel = (int*)ws;            ws += (size_t)NE * 4;         // 2.56 MB
    unsigned short* xh     = (unsigned short*)ws; ws += (size_t)NN * 128 * 2;   // 12.8 MB
    unsigned short* h1b    = (unsigned short*)ws;                               // 12.8 MB

    // CSR by (dst, rel) — hierarchical scan, fully parallel
    hipMemsetAsync(cnt, 0, (size_t)SCAN_N * 4, stream);
    count_kernel<<<(NE + 255) / 256, 256, 0, stream>>>(edst, etyp, cnt, NE);
    inv_kernel<<<(SCAN_N + 255) / 256, 256, 0, stream>>>(cnt, inv, SCAN_N);
    scan1_kernel<<<SCAN_NB, 256, 0, stream>>>(cnt, rp, bsum);
    scan2_kernel<<<1, 256, 0, stream>>>(bsum, boff, SCAN_NB);
    scan3_kernel<<<SCAN_NB, 256, 0, stream>>>(rp, start, boff, SCAN_NB);
    fill_kernel<<<(NE + 255) / 256, 256, 0, stream>>>(esrc, edst, etyp, start, srcrel, NE);

    // fp16 conversions / packs
    cvt_kernel<<<(NN * 32 + 255) / 256, 256, 0, stream>>>(x, xh, NN * 32);
    pack_b_kernel<<<(1152 * 128 + 255) / 256, 256, 0, stream>>>(W1, root1, Bt1, 128);
    pack_b_kernel<<<(576 * 128 + 255) / 256, 256, 0, stream>>>(W2, root2, Bt2, 64);

    const int fgrid = (NN + 31) / 32;  // 1563 blocks of 32 dst

    // layer 1: aggregate-first fused (mean_r(x) @ W_r + x @ root1 + b1) -> h1b fp16
    fused_layer<128, false><<<fgrid, 256, 0, stream>>>(rp, srcrel, inv, xh, Bt1, b1, h1b);
    // layer 2: same on h1b, + sigmoid -> out fp32
    fused_layer<64, true><<<fgrid, 256, 0, stream>>>(rp, srcrel, inv, h1b, Bt2, b2, out);
}

// Round 2
// 557.404 us; speedup vs baseline: 1.0828x; 1.0828x over previous
//
#include <hip/hip_runtime.h>
#include <math.h>

#define NN 50000
#define NE 640000
#define NR 8
#define SCAN_N (NN * NR)  // 400000 segments
#define SCAN_CH 2048      // elements per scan block
#define SCAN_NB ((SCAN_N + SCAN_CH - 1) / SCAN_CH)  // 196

typedef __attribute__((ext_vector_type(8))) _Float16 half8;
typedef __attribute__((ext_vector_type(8))) short short8;
typedef __attribute__((ext_vector_type(4))) float f32x4;

__device__ __forceinline__ unsigned short f2h(float f) {
    _Float16 h = (_Float16)f;                       // v_cvt_f16_f32, RNE
    return __builtin_bit_cast(unsigned short, h);
}
__device__ __forceinline__ float h2f(unsigned short u) {
    return (float)__builtin_bit_cast(_Float16, u);
}

// ---------- preprocessing ----------
__global__ __launch_bounds__(256) void count_kernel(const int* __restrict__ dst,
                                                    const int* __restrict__ typ,
                                                    int* __restrict__ cnt, int E) {
    int e = blockIdx.x * 256 + threadIdx.x;
    if (e < E) atomicAdd(&cnt[dst[e] * NR + typ[e]], 1);
}

__global__ __launch_bounds__(256) void inv_kernel(const int* __restrict__ cnt,
                                                  float* __restrict__ inv, int n) {
    int i = blockIdx.x * 256 + threadIdx.x;
    if (i < n) {
        int c = cnt[i];
        inv[i] = 1.0f / (float)(c > 1 ? c : 1);
    }
}

// ---- hierarchical scan
__global__ __launch_bounds__(256) void scan1_kernel(const int* __restrict__ cnt,
                                                    int* __restrict__ loc,
                                                    int* __restrict__ bsum) {
    __shared__ int s[256];
    const int t = threadIdx.x;
    const int base = blockIdx.x * SCAN_CH + t * 8;
    int v[8];
    int sum = 0;
#pragma unroll
    for (int j = 0; j < 8; ++j) {
        int idx = base + j;
        v[j] = (idx < SCAN_N) ? cnt[idx] : 0;
        sum += v[j];
    }
    s[t] = sum;
    __syncthreads();
    for (int off = 1; off < 256; off <<= 1) {
        int u = (t >= off) ? s[t - off] : 0;
        __syncthreads();
        s[t] += u;
        __syncthreads();
    }
    int run = (t == 0) ? 0 : s[t - 1];
#pragma unroll
    for (int j = 0; j < 8; ++j) {
        int idx = base + j;
        if (idx < SCAN_N) loc[idx] = run;
        run += v[j];
    }
    if (t == 255) bsum[blockIdx.x] = s[255];
}

__global__ __launch_bounds__(256) void scan2_kernel(const int* __restrict__ bsum,
                                                    int* __restrict__ boff, int nb) {
    __shared__ int s[256];
    const int t = threadIdx.x;
    s[t] = (t < nb) ? bsum[t] : 0;
    __syncthreads();
    for (int off = 1; off < 256; off <<= 1) {
        int u = (t >= off) ? s[t - off] : 0;
        __syncthreads();
        s[t] += u;
        __syncthreads();
    }
    if (t < nb) boff[t] = (t == 0) ? 0 : s[t - 1];
    if (t == nb - 1) boff[nb] = s[t];
}

__global__ __launch_bounds__(256) void scan3_kernel(int* __restrict__ rowptr,
                                                    int* __restrict__ start,
                                                    const int* __restrict__ boff, int nb) {
    const int b = blockIdx.x, t = threadIdx.x;
    const int add = boff[b];
#pragma unroll
    for (int j = 0; j < 8; ++j) {
        int idx = b * SCAN_CH + t * 8 + j;
        if (idx < SCAN_N) {
            int v = rowptr[idx] + add;
            rowptr[idx] = v;
            start[idx] = v;
        }
    }
    if (b == 0 && t == 0) rowptr[SCAN_N] = boff[nb];
}

// counting-sort by (dst,rel): srcrel[pos] = src | rel<<20
__global__ __launch_bounds__(256) void fill_kernel(const int* __restrict__ src,
                                                   const int* __restrict__ dst,
                                                   const int* __restrict__ typ,
                                                   int* __restrict__ start,
                                                   int* __restrict__ srcrel, int E) {
    int e = blockIdx.x * 256 + threadIdx.x;
    if (e >= E) return;
    int r = typ[e];
    int pos = atomicAdd(&start[dst[e] * NR + r], 1);
    srcrel[pos] = src[e] | (r << 20);
}

// ---------- x (fp32, [NN,128]) -> xh (fp16) ----------
__global__ __launch_bounds__(256) void cvt_kernel(const float* __restrict__ x,
                                                  unsigned short* __restrict__ xh, int n4) {
    int i = blockIdx.x * 256 + threadIdx.x;
    if (i >= n4) return;
    float4 v = ((const float4*)x)[i];
    uint2 u;
    u.x = (unsigned)f2h(v.x) | ((unsigned)f2h(v.y) << 16);
    u.y = (unsigned)f2h(v.z) | ((unsigned)f2h(v.w) << 16);
    ((uint2*)xh)[i] = u;
}

// ---------- weight pack: Bt[n][k] fp16, n in [0,9*O): n<8*O -> W[r=n/O][k][o=n%O], else root[k][n-8*O]
__global__ __launch_bounds__(256) void pack_b_kernel(const float* __restrict__ W,
                                                     const float* __restrict__ root,
                                                     unsigned short* __restrict__ Bt, int O) {
    int i = blockIdx.x * 256 + threadIdx.x;
    int NTOT = 9 * O;
    if (i >= NTOT * 128) return;
    int k = i & 127, n = i >> 7;
    float v = (n < 8 * O) ? W[(size_t)(n / O) * 128 * O + (size_t)k * O + (n % O)]
                          : root[(size_t)k * O + (n - 8 * O)];
    Bt[(size_t)n * 128 + k] = f2h(v);
}

// ---------- fused aggregate-first RGCN layer ----------
// h[dst] = sum_r (mean_{src in N_r(dst)} X[src]) @ W_r + X[dst] @ root + b  (+ sigmoid)
// Block: 16 dst, 8 waves (512 thr), 32 KB LDS -> 3 blocks/CU (24 waves/CU).
// Phase 1: each wave gathers+means 2 dst into LDS tile A[16][8*128] fp16
// (XOR-swizzled). Phase 2: 16xO GEMM, K=9*128 (root streamed from global),
// MFMA 16x16x32 f16. O=128: wave w -> 16-col tile, full K. O=64: 4 col tiles
// x 2-way K-split, LDS partial reduce. Bias/sigmoid in epilogue.
#define ACC_EDGE(P, G)                                                        \
    do {                                                                      \
        unsigned r_ = ((unsigned)(P)) >> 20;                                  \
        float vx_ = h2f((unsigned short)((G) & 0xFFFFu));                     \
        float vy_ = h2f((unsigned short)((G) >> 16));                         \
        switch (r_) {                                                         \
            case 0: acc[0].x += vx_; acc[0].y += vy_; break;                  \
            case 1: acc[1].x += vx_; acc[1].y += vy_; break;                  \
            case 2: acc[2].x += vx_; acc[2].y += vy_; break;                  \
            case 3: acc[3].x += vx_; acc[3].y += vy_; break;                  \
            case 4: acc[4].x += vx_; acc[4].y += vy_; break;                  \
            case 5: acc[5].x += vx_; acc[5].y += vy_; break;                  \
            case 6: acc[6].x += vx_; acc[6].y += vy_; break;                  \
            default: acc[7].x += vx_; acc[7].y += vy_; break;                 \
        }                                                                     \
    } while (0)

template <int O, bool FINAL>
__global__ __launch_bounds__(512, 6) void fused_layer(
    const int* __restrict__ rp, const int* __restrict__ srcrel,
    const float* __restrict__ inv, const unsigned short* __restrict__ X,
    const unsigned short* __restrict__ Bt, const float* __restrict__ bias,
    void* __restrict__ Hout) {
    __shared__ __align__(16) unsigned short As[16 * 1024];      // 32 KB
    __shared__ float pbuf[FINAL ? 4 * 16 * 16 : 4];             // 4 KB (O=64 only)
    const int t = threadIdx.x;
    const int w = t >> 6, lane = t & 63;
    const int bm = blockIdx.x * 16;                              // 50000 % 16 == 0
    const unsigned* X2 = (const unsigned*)X;  // half2 view, row stride 64

    // ---- phase 1: 2 dst per wave ----
#pragma unroll
    for (int i = 0; i < 2; ++i) {
        const int m = w * 2 + i;  // local LDS row 0..15
        const int d = bm + m;
        float2 acc[8];
#pragma unroll
        for (int r = 0; r < 8; ++r) acc[r] = make_float2(0.f, 0.f);

        const int beg = rp[d * 8], end = rp[d * 8 + 8];
        for (int base = beg; base < end; base += 64) {
            int nv = end - base;
            nv = nv > 64 ? 64 : nv;
            int idx = base + (lane < nv ? lane : nv - 1);
            int pv = srcrel[idx];  // batched edge records, one per lane
            int j = 0;
            for (; j + 3 < nv; j += 4) {
                int p0 = __builtin_amdgcn_readlane(pv, j);
                int p1 = __builtin_amdgcn_readlane(pv, j + 1);
                int p2 = __builtin_amdgcn_readlane(pv, j + 2);
                int p3 = __builtin_amdgcn_readlane(pv, j + 3);
                unsigned g0 = X2[(p0 & 0xFFFFF) * 64 + lane];
                unsigned g1 = X2[(p1 & 0xFFFFF) * 64 + lane];
                unsigned g2 = X2[(p2 & 0xFFFFF) * 64 + lane];
                unsigned g3 = X2[(p3 & 0xFFFFF) * 64 + lane];
                ACC_EDGE(p0, g0);
                ACC_EDGE(p1, g1);
                ACC_EDGE(p2, g2);
                ACC_EDGE(p3, g3);
            }
            for (; j < nv; ++j) {
                int p0 = __builtin_amdgcn_readlane(pv, j);
                unsigned g0 = X2[(p0 & 0xFFFFF) * 64 + lane];
                ACC_EDGE(p0, g0);
            }
        }
        // scale by 1/cnt, fp16-pack, swizzled LDS store (conflict-free)
        char* rowp = (char*)As + m * 2048;
        const int swz = (m & 7) << 4;
#pragma unroll
        for (int r = 0; r < 8; ++r) {
            float iv = inv[d * 8 + r];
            unsigned u = (unsigned)f2h(acc[r].x * iv) |
                         ((unsigned)f2h(acc[r].y * iv) << 16);
            *(unsigned*)(rowp + ((r * 256 + lane * 4) ^ swz)) = u;
        }
    }
    __syncthreads();

    // ---- phase 2: [16 x 9*128] @ Bt^T -> [16 x O] ----
    const int q = lane >> 4, ml = lane & 15;
    int col, ksb;
    if (O == 128) {            // 8 waves x one 16-col tile, full K (36 ksteps)
        col = w * 16;
        ksb = 0;
    } else {                   // 4 col tiles x 2 K-groups of 18 ksteps
        col = (w & 3) * 16;
        ksb = (w >> 2) * 18;
    }
    constexpr int NKS = (O == 128) ? 36 : 18;

    f32x4 acc0 = (f32x4)0.f, acc1 = (f32x4)0.f;
    const unsigned short* Xroot = X + (size_t)(bm + ml) * 128;
    const char* arowp = (const char*)As + ml * 2048;
    const int aswz = (ml & 7) << 4;

#pragma unroll 6
    for (int u = 0; u < NKS; ++u) {
        int ks = ksb + u;
        int r = ks >> 2, kk = ks & 3;
        half8 af;
        if (r < 8) {
            af = __builtin_bit_cast(
                half8,
                *(const short8*)(arowp + ((r * 256 + kk * 64 + q * 16) ^ aswz)));
        } else {
            af = __builtin_bit_cast(half8,
                                    *(const short8*)(Xroot + kk * 32 + q * 8));
        }
        half8 bf = __builtin_bit_cast(
            half8,
            *(const short8*)(Bt + (size_t)(r * O + col + ml) * 128 + kk * 32 +
                             q * 8));
        if (u & 1)
            acc1 = __builtin_amdgcn_mfma_f32_16x16x32_f16(af, bf, acc1, 0, 0, 0);
        else
            acc0 = __builtin_amdgcn_mfma_f32_16x16x32_f16(af, bf, acc0, 0, 0, 0);
    }
    f32x4 accv = acc0 + acc1;

    // epilogue: C/D layout col=lane&15, row=q*4+j
    if (!FINAL) {
        float bv = bias[col + ml];
#pragma unroll
        for (int j = 0; j < 4; ++j) {
            int grow = bm + q * 4 + j;
            ((unsigned short*)Hout)[(size_t)grow * O + col + ml] =
                f2h(accv[j] + bv);
        }
    } else {
        const int kg = w >> 2, ci = w & 3;
        if (kg == 1) {
#pragma unroll
            for (int j = 0; j < 4; ++j)
                pbuf[ci * 256 + (q * 4 + j) * 16 + ml] = accv[j];
        }
        __syncthreads();
        if (kg == 0) {
            float bv = bias[col + ml];
#pragma unroll
            for (int j = 0; j < 4; ++j) {
                int grow = bm + q * 4 + j;
                float v = accv[j] + pbuf[ci * 256 + (q * 4 + j) * 16 + ml] + bv;
                ((float*)Hout)[(size_t)grow * O + col + ml] =
                    1.f / (1.f + __expf(-v));
            }
        }
    }
}

extern "C" void kernel_launch(void* const* d_in, const int* in_sizes, int n_in,
                              void* d_out, int out_size, void* d_ws, size_t ws_size,
                              hipStream_t stream) {
    const float* x     = (const float*)d_in[0];
    const int*   esrc  = (const int*)d_in[1];
    const int*   edst  = (const int*)d_in[2];
    const int*   etyp  = (const int*)d_in[3];
    const float* W1    = (const float*)d_in[4];
    const float* root1 = (const float*)d_in[5];
    const float* b1    = (const float*)d_in[6];
    const float* W2    = (const float*)d_in[7];
    const float* root2 = (const float*)d_in[8];
    const float* b2    = (const float*)d_in[9];
    float* out = (float*)d_out;

    char* ws = (char*)d_ws;
    unsigned short* Bt1    = (unsigned short*)ws; ws += (size_t)1152 * 128 * 2; // 288 KB
    unsigned short* Bt2    = (unsigned short*)ws; ws += (size_t)576 * 128 * 2;  // 144 KB
    int*            cnt    = (int*)ws;            ws += (size_t)SCAN_N * 4;     // 1.6 MB
    float*          inv    = (float*)ws;          ws += (size_t)SCAN_N * 4;     // 1.6 MB
    int*            rp     = (int*)ws;            ws += (size_t)(SCAN_N + 64) * 4;
    int*            start  = (int*)ws;            ws += (size_t)SCAN_N * 4;     // 1.6 MB
    int*            bsum   = (int*)ws;            ws += (size_t)256 * 4;
    int*            boff   = (int*)ws;            ws += (size_t)257 * 4;
    int*            srcrel = (int*)ws;            ws += (size_t)NE * 4;         // 2.56 MB
    unsigned short* xh     = (unsigned short*)ws; ws += (size_t)NN * 128 * 2;   // 12.8 MB
    unsigned short* h1b    = (unsigned short*)ws;                               // 12.8 MB

    // CSR by (dst, rel) — hierarchical scan, fully parallel
    hipMemsetAsync(cnt, 0, (size_t)SCAN_N * 4, stream);
    count_kernel<<<(NE + 255) / 256, 256, 0, stream>>>(edst, etyp, cnt, NE);
    inv_kernel<<<(SCAN_N + 255) / 256, 256, 0, stream>>>(cnt, inv, SCAN_N);
    scan1_kernel<<<SCAN_NB, 256, 0, stream>>>(cnt, rp, bsum);
    scan2_kernel<<<1, 256, 0, stream>>>(bsum, boff, SCAN_NB);
    scan3_kernel<<<SCAN_NB, 256, 0, stream>>>(rp, start, boff, SCAN_NB);
    fill_kernel<<<(NE + 255) / 256, 256, 0, stream>>>(esrc, edst, etyp, start, srcrel, NE);

    // fp16 conversions / packs
    cvt_kernel<<<(NN * 32 + 255) / 256, 256, 0, stream>>>(x, xh, NN * 32);
    pack_b_kernel<<<(1152 * 128 + 255) / 256, 256, 0, stream>>>(W1, root1, Bt1, 128);
    pack_b_kernel<<<(576 * 128 + 255) / 256, 256, 0, stream>>>(W2, root2, Bt2, 64);

    const int fgrid = NN / 16;  // 3125 blocks of 16 dst, 512 threads

    // layer 1: aggregate-first fused (mean_r(x) @ W_r + x @ root1 + b1) -> h1b fp16
    fused_layer<128, false><<<fgrid, 512, 0, stream>>>(rp, srcrel, inv, xh, Bt1, b1, h1b);
    // layer 2: same on h1b, + sigmoid -> out fp32
    fused_layer<64, true><<<fgrid, 512, 0, stream>>>(rp, srcrel, inv, h1b, Bt2, b2, out);
}

// Round 3
// 413.034 us; speedup vs baseline: 1.4613x; 1.3495x over previous
//
#include <hip/hip_runtime.h>
#include <math.h>

#define NN 50000
#define NE 640000
#define NR 8
#define SCAN_N (NN * NR)  // 400000 segments
#define SCAN_CH 2048      // elements per scan block
#define SCAN_NB ((SCAN_N + SCAN_CH - 1) / SCAN_CH)  // 196

typedef __attribute__((ext_vector_type(8))) _Float16 half8;
typedef __attribute__((ext_vector_type(8))) short short8;
typedef __attribute__((ext_vector_type(4))) float f32x4;

__device__ __forceinline__ unsigned short f2h(float f) {
    _Float16 h = (_Float16)f;                       // v_cvt_f16_f32, RNE
    return __builtin_bit_cast(unsigned short, h);
}
__device__ __forceinline__ float h2f(unsigned short u) {
    return (float)__builtin_bit_cast(_Float16, u);
}

// ---------- preprocessing ----------
__global__ __launch_bounds__(256) void count_kernel(const int* __restrict__ dst,
                                                    const int* __restrict__ typ,
                                                    int* __restrict__ cnt, int E) {
    int e = blockIdx.x * 256 + threadIdx.x;
    if (e < E) atomicAdd(&cnt[dst[e] * NR + typ[e]], 1);
}

__global__ __launch_bounds__(256) void inv_kernel(const int* __restrict__ cnt,
                                                  float* __restrict__ inv, int n) {
    int i = blockIdx.x * 256 + threadIdx.x;
    if (i < n) {
        int c = cnt[i];
        inv[i] = 1.0f / (float)(c > 1 ? c : 1);
    }
}

// ---- hierarchical scan
__global__ __launch_bounds__(256) void scan1_kernel(const int* __restrict__ cnt,
                                                    int* __restrict__ loc,
                                                    int* __restrict__ bsum) {
    __shared__ int s[256];
    const int t = threadIdx.x;
    const int base = blockIdx.x * SCAN_CH + t * 8;
    int v[8];
    int sum = 0;
#pragma unroll
    for (int j = 0; j < 8; ++j) {
        int idx = base + j;
        v[j] = (idx < SCAN_N) ? cnt[idx] : 0;
        sum += v[j];
    }
    s[t] = sum;
    __syncthreads();
    for (int off = 1; off < 256; off <<= 1) {
        int u = (t >= off) ? s[t - off] : 0;
        __syncthreads();
        s[t] += u;
        __syncthreads();
    }
    int run = (t == 0) ? 0 : s[t - 1];
#pragma unroll
    for (int j = 0; j < 8; ++j) {
        int idx = base + j;
        if (idx < SCAN_N) loc[idx] = run;
        run += v[j];
    }
    if (t == 255) bsum[blockIdx.x] = s[255];
}

__global__ __launch_bounds__(256) void scan2_kernel(const int* __restrict__ bsum,
                                                    int* __restrict__ boff, int nb) {
    __shared__ int s[256];
    const int t = threadIdx.x;
    s[t] = (t < nb) ? bsum[t] : 0;
    __syncthreads();
    for (int off = 1; off < 256; off <<= 1) {
        int u = (t >= off) ? s[t - off] : 0;
        __syncthreads();
        s[t] += u;
        __syncthreads();
    }
    if (t < nb) boff[t] = (t == 0) ? 0 : s[t - 1];
    if (t == nb - 1) boff[nb] = s[t];
}

__global__ __launch_bounds__(256) void scan3_kernel(int* __restrict__ rowptr,
                                                    int* __restrict__ start,
                                                    const int* __restrict__ boff, int nb) {
    const int b = blockIdx.x, t = threadIdx.x;
    const int add = boff[b];
#pragma unroll
    for (int j = 0; j < 8; ++j) {
        int idx = b * SCAN_CH + t * 8 + j;
        if (idx < SCAN_N) {
            int v = rowptr[idx] + add;
            rowptr[idx] = v;
            start[idx] = v;
        }
    }
    if (b == 0 && t == 0) rowptr[SCAN_N] = boff[nb];
}

// counting-sort by (dst,rel): srcrel[pos] = src | rel<<20
__global__ __launch_bounds__(256) void fill_kernel(const int* __restrict__ src,
                                                   const int* __restrict__ dst,
                                                   const int* __restrict__ typ,
                                                   int* __restrict__ start,
                                                   int* __restrict__ srcrel, int E) {
    int e = blockIdx.x * 256 + threadIdx.x;
    if (e >= E) return;
    int r = typ[e];
    int pos = atomicAdd(&start[dst[e] * NR + r], 1);
    srcrel[pos] = src[e] | (r << 20);
}

// ---------- x (fp32, [NN,128]) -> xh (fp16) ----------
__global__ __launch_bounds__(256) void cvt_kernel(const float* __restrict__ x,
                                                  unsigned short* __restrict__ xh, int n4) {
    int i = blockIdx.x * 256 + threadIdx.x;
    if (i >= n4) return;
    float4 v = ((const float4*)x)[i];
    uint2 u;
    u.x = (unsigned)f2h(v.x) | ((unsigned)f2h(v.y) << 16);
    u.y = (unsigned)f2h(v.z) | ((unsigned)f2h(v.w) << 16);
    ((uint2*)xh)[i] = u;
}

// ---------- weight pack: Bt[n][k] fp16, n in [0,9*O): n<8*O -> W[r=n/O][k][o=n%O], else root[k][n-8*O]
__global__ __launch_bounds__(256) void pack_b_kernel(const float* __restrict__ W,
                                                     const float* __restrict__ root,
                                                     unsigned short* __restrict__ Bt, int O) {
    int i = blockIdx.x * 256 + threadIdx.x;
    int NTOT = 9 * O;
    if (i >= NTOT * 128) return;
    int k = i & 127, n = i >> 7;
    float v = (n < 8 * O) ? W[(size_t)(n / O) * 128 * O + (size_t)k * O + (n % O)]
                          : root[(size_t)k * O + (n - 8 * O)];
    Bt[(size_t)n * 128 + k] = f2h(v);
}

// ---------- fused aggregate-first RGCN layer ----------
// h[dst] = sum_r (mean_{src in N_r(dst)} X[src]) @ W_r + X[dst] @ root + b  (+ sigmoid)
// Block: 16 dst, 8 waves (512 thr), 36 KB LDS -> 4 blocks/CU (32 waves/CU).
// Phase 1: each wave gathers+means 2 dst into LDS tile A[16][8*128] fp16
// (XOR-swizzled). NAMED per-relation accumulators (a0..a7) — an acc[8] array
// gets canonicalized to dynamic indexing and spills to scratch (r2: VGPR 88->40,
// WRITE_SIZE 12.5->185 MB). 8 gathers in flight for latency hiding.
// Phase 2: 16xO GEMM, K=9*128 (root streamed from global), MFMA 16x16x32 f16.
#define ACC_EDGE(P, G)                                                        \
    do {                                                                      \
        unsigned r_ = ((unsigned)(P)) >> 20;                                  \
        float vx_ = h2f((unsigned short)((G) & 0xFFFFu));                     \
        float vy_ = h2f((unsigned short)((G) >> 16));                         \
        switch (r_) {                                                         \
            case 0: a0x += vx_; a0y += vy_; break;                            \
            case 1: a1x += vx_; a1y += vy_; break;                            \
            case 2: a2x += vx_; a2y += vy_; break;                            \
            case 3: a3x += vx_; a3y += vy_; break;                            \
            case 4: a4x += vx_; a4y += vy_; break;                            \
            case 5: a5x += vx_; a5y += vy_; break;                            \
            case 6: a6x += vx_; a6y += vy_; break;                            \
            default: a7x += vx_; a7y += vy_; break;                           \
        }                                                                     \
    } while (0)

#define STORE_ROW(R, AX, AY)                                                  \
    do {                                                                      \
        unsigned u_ = (unsigned)f2h((AX) * iv##R) |                           \
                      ((unsigned)f2h((AY) * iv##R) << 16);                    \
        *(unsigned*)(rowp + (((R)*256 + lane * 4) ^ swz)) = u_;               \
    } while (0)

template <int O, bool FINAL>
__global__ __launch_bounds__(512, 8) void fused_layer(
    const int* __restrict__ rp, const int* __restrict__ srcrel,
    const float* __restrict__ inv, const unsigned short* __restrict__ X,
    const unsigned short* __restrict__ Bt, const float* __restrict__ bias,
    void* __restrict__ Hout) {
    __shared__ __align__(16) unsigned short As[16 * 1024];      // 32 KB
    __shared__ float pbuf[FINAL ? 4 * 16 * 16 : 4];             // 4 KB (O=64 only)
    const int t = threadIdx.x;
    const int w = t >> 6, lane = t & 63;
    const int bm = blockIdx.x * 16;                              // 50000 % 16 == 0
    const unsigned* X2 = (const unsigned*)X;  // half2 view, row stride 64

    // ---- phase 1: 2 dst per wave ----
    for (int i = 0; i < 2; ++i) {
        const int m = w * 2 + i;  // local LDS row 0..15
        const int d = bm + m;
        float a0x = 0.f, a0y = 0.f, a1x = 0.f, a1y = 0.f;
        float a2x = 0.f, a2y = 0.f, a3x = 0.f, a3y = 0.f;
        float a4x = 0.f, a4y = 0.f, a5x = 0.f, a5y = 0.f;
        float a6x = 0.f, a6y = 0.f, a7x = 0.f, a7y = 0.f;

        // preload per-(dst,rel) inverse counts (off the flush critical path)
        const float iv0 = inv[d * 8 + 0], iv1 = inv[d * 8 + 1];
        const float iv2 = inv[d * 8 + 2], iv3 = inv[d * 8 + 3];
        const float iv4 = inv[d * 8 + 4], iv5 = inv[d * 8 + 5];
        const float iv6 = inv[d * 8 + 6], iv7 = inv[d * 8 + 7];

        const int beg = rp[d * 8], end = rp[d * 8 + 8];
        for (int base = beg; base < end; base += 64) {
            int nv = end - base;
            nv = nv > 64 ? 64 : nv;
            int idx = base + (lane < nv ? lane : nv - 1);
            int pv = srcrel[idx];  // batched edge records, one per lane
            int j = 0;
            for (; j + 7 < nv; j += 8) {   // 8 gathers in flight
                int p0 = __builtin_amdgcn_readlane(pv, j);
                int p1 = __builtin_amdgcn_readlane(pv, j + 1);
                int p2 = __builtin_amdgcn_readlane(pv, j + 2);
                int p3 = __builtin_amdgcn_readlane(pv, j + 3);
                int p4 = __builtin_amdgcn_readlane(pv, j + 4);
                int p5 = __builtin_amdgcn_readlane(pv, j + 5);
                int p6 = __builtin_amdgcn_readlane(pv, j + 6);
                int p7 = __builtin_amdgcn_readlane(pv, j + 7);
                unsigned g0 = X2[(p0 & 0xFFFFF) * 64 + lane];
                unsigned g1 = X2[(p1 & 0xFFFFF) * 64 + lane];
                unsigned g2 = X2[(p2 & 0xFFFFF) * 64 + lane];
                unsigned g3 = X2[(p3 & 0xFFFFF) * 64 + lane];
                unsigned g4 = X2[(p4 & 0xFFFFF) * 64 + lane];
                unsigned g5 = X2[(p5 & 0xFFFFF) * 64 + lane];
                unsigned g6 = X2[(p6 & 0xFFFFF) * 64 + lane];
                unsigned g7 = X2[(p7 & 0xFFFFF) * 64 + lane];
                ACC_EDGE(p0, g0);
                ACC_EDGE(p1, g1);
                ACC_EDGE(p2, g2);
                ACC_EDGE(p3, g3);
                ACC_EDGE(p4, g4);
                ACC_EDGE(p5, g5);
                ACC_EDGE(p6, g6);
                ACC_EDGE(p7, g7);
            }
            for (; j + 3 < nv; j += 4) {
                int p0 = __builtin_amdgcn_readlane(pv, j);
                int p1 = __builtin_amdgcn_readlane(pv, j + 1);
                int p2 = __builtin_amdgcn_readlane(pv, j + 2);
                int p3 = __builtin_amdgcn_readlane(pv, j + 3);
                unsigned g0 = X2[(p0 & 0xFFFFF) * 64 + lane];
                unsigned g1 = X2[(p1 & 0xFFFFF) * 64 + lane];
                unsigned g2 = X2[(p2 & 0xFFFFF) * 64 + lane];
                unsigned g3 = X2[(p3 & 0xFFFFF) * 64 + lane];
                ACC_EDGE(p0, g0);
                ACC_EDGE(p1, g1);
                ACC_EDGE(p2, g2);
                ACC_EDGE(p3, g3);
            }
            for (; j < nv; ++j) {
                int p0 = __builtin_amdgcn_readlane(pv, j);
                unsigned g0 = X2[(p0 & 0xFFFFF) * 64 + lane];
                ACC_EDGE(p0, g0);
            }
        }
        // scale by 1/cnt, fp16-pack, swizzled LDS store (conflict-free)
        char* rowp = (char*)As + m * 2048;
        const int swz = (m & 7) << 4;
        STORE_ROW(0, a0x, a0y);
        STORE_ROW(1, a1x, a1y);
        STORE_ROW(2, a2x, a2y);
        STORE_ROW(3, a3x, a3y);
        STORE_ROW(4, a4x, a4y);
        STORE_ROW(5, a5x, a5y);
        STORE_ROW(6, a6x, a6y);
        STORE_ROW(7, a7x, a7y);
    }
    __syncthreads();

    // ---- phase 2: [16 x 9*128] @ Bt^T -> [16 x O] ----
    const int q = lane >> 4, ml = lane & 15;
    int col, ksb;
    if (O == 128) {            // 8 waves x one 16-col tile, full K (36 ksteps)
        col = w * 16;
        ksb = 0;
    } else {                   // 4 col tiles x 2 K-groups of 18 ksteps
        col = (w & 3) * 16;
        ksb = (w >> 2) * 18;
    }
    constexpr int NKS = (O == 128) ? 36 : 18;

    f32x4 acc0 = (f32x4)0.f, acc1 = (f32x4)0.f;
    const unsigned short* Xroot = X + (size_t)(bm + ml) * 128;
    const char* arowp = (const char*)As + ml * 2048;
    const int aswz = (ml & 7) << 4;

#pragma unroll 6
    for (int u = 0; u < NKS; ++u) {
        int ks = ksb + u;
        int r = ks >> 2, kk = ks & 3;
        half8 af;
        if (r < 8) {
            af = __builtin_bit_cast(
                half8,
                *(const short8*)(arowp + ((r * 256 + kk * 64 + q * 16) ^ aswz)));
        } else {
            af = __builtin_bit_cast(half8,
                                    *(const short8*)(Xroot + kk * 32 + q * 8));
        }
        half8 bf = __builtin_bit_cast(
            half8,
            *(const short8*)(Bt + (size_t)(r * O + col + ml) * 128 + kk * 32 +
                             q * 8));
        if (u & 1)
            acc1 = __builtin_amdgcn_mfma_f32_16x16x32_f16(af, bf, acc1, 0, 0, 0);
        else
            acc0 = __builtin_amdgcn_mfma_f32_16x16x32_f16(af, bf, acc0, 0, 0, 0);
    }
    f32x4 accv = acc0 + acc1;

    // epilogue: C/D layout col=lane&15, row=q*4+j
    if (!FINAL) {
        float bv = bias[col + ml];
#pragma unroll
        for (int j = 0; j < 4; ++j) {
            int grow = bm + q * 4 + j;
            ((unsigned short*)Hout)[(size_t)grow * O + col + ml] =
                f2h(accv[j] + bv);
        }
    } else {
        const int kg = w >> 2, ci = w & 3;
        if (kg == 1) {
#pragma unroll
            for (int j = 0; j < 4; ++j)
                pbuf[ci * 256 + (q * 4 + j) * 16 + ml] = accv[j];
        }
        __syncthreads();
        if (kg == 0) {
            float bv = bias[col + ml];
#pragma unroll
            for (int j = 0; j < 4; ++j) {
                int grow = bm + q * 4 + j;
                float v = accv[j] + pbuf[ci * 256 + (q * 4 + j) * 16 + ml] + bv;
                ((float*)Hout)[(size_t)grow * O + col + ml] =
                    1.f / (1.f + __expf(-v));
            }
        }
    }
}

extern "C" void kernel_launch(void* const* d_in, const int* in_sizes, int n_in,
                              void* d_out, int out_size, void* d_ws, size_t ws_size,
                              hipStream_t stream) {
    const float* x     = (const float*)d_in[0];
    const int*   esrc  = (const int*)d_in[1];
    const int*   edst  = (const int*)d_in[2];
    const int*   etyp  = (const int*)d_in[3];
    const float* W1    = (const float*)d_in[4];
    const float* root1 = (const float*)d_in[5];
    const float* b1    = (const float*)d_in[6];
    const float* W2    = (const float*)d_in[7];
    const float* root2 = (const float*)d_in[8];
    const float* b2    = (const float*)d_in[9];
    float* out = (float*)d_out;

    char* ws = (char*)d_ws;
    unsigned short* Bt1    = (unsigned short*)ws; ws += (size_t)1152 * 128 * 2; // 288 KB
    unsigned short* Bt2    = (unsigned short*)ws; ws += (size_t)576 * 128 * 2;  // 144 KB
    int*            cnt    = (int*)ws;            ws += (size_t)SCAN_N * 4;     // 1.6 MB
    float*          inv    = (float*)ws;          ws += (size_t)SCAN_N * 4;     // 1.6 MB
    int*            rp     = (int*)ws;            ws += (size_t)(SCAN_N + 64) * 4;
    int*            start  = (int*)ws;            ws += (size_t)SCAN_N * 4;     // 1.6 MB
    int*            bsum   = (int*)ws;            ws += (size_t)256 * 4;
    int*            boff   = (int*)ws;            ws += (size_t)257 * 4;
    int*            srcrel = (int*)ws;            ws += (size_t)NE * 4;         // 2.56 MB
    unsigned short* xh     = (unsigned short*)ws; ws += (size_t)NN * 128 * 2;   // 12.8 MB
    unsigned short* h1b    = (unsigned short*)ws;                               // 12.8 MB

    // CSR by (dst, rel) — hierarchical scan, fully parallel
    hipMemsetAsync(cnt, 0, (size_t)SCAN_N * 4, stream);
    count_kernel<<<(NE + 255) / 256, 256, 0, stream>>>(edst, etyp, cnt, NE);
    inv_kernel<<<(SCAN_N + 255) / 256, 256, 0, stream>>>(cnt, inv, SCAN_N);
    scan1_kernel<<<SCAN_NB, 256, 0, stream>>>(cnt, rp, bsum);
    scan2_kernel<<<1, 256, 0, stream>>>(bsum, boff, SCAN_NB);
    scan3_kernel<<<SCAN_NB, 256, 0, stream>>>(rp, start, boff, SCAN_NB);
    fill_kernel<<<(NE + 255) / 256, 256, 0, stream>>>(esrc, edst, etyp, start, srcrel, NE);

    // fp16 conversions / packs
    cvt_kernel<<<(NN * 32 + 255) / 256, 256, 0, stream>>>(x, xh, NN * 32);
    pack_b_kernel<<<(1152 * 128 + 255) / 256, 256, 0, stream>>>(W1, root1, Bt1, 128);
    pack_b_kernel<<<(576 * 128 + 255) / 256, 256, 0, stream>>>(W2, root2, Bt2, 64);

    const int fgrid = NN / 16;  // 3125 blocks of 16 dst, 512 threads

    // layer 1: aggregate-first fused (mean_r(x) @ W_r + x @ root1 + b1) -> h1b fp16
    fused_layer<128, false><<<fgrid, 512, 0, stream>>>(rp, srcrel, inv, xh, Bt1, b1, h1b);
    // layer 2: same on h1b, + sigmoid -> out fp32
    fused_layer<64, true><<<fgrid, 512, 0, stream>>>(rp, srcrel, inv, h1b, Bt2, b2, out);
}

// Round 4
// 402.599 us; speedup vs baseline: 1.4992x; 1.0259x over previous
//
#include <hip/hip_runtime.h>
#include <math.h>

#define NN 50000
#define NE 640000
#define NR 8
#define SCAN_N (NN * NR)  // 400000 segments
#define SCAN_CH 2048      // elements per scan block
#define SCAN_NB ((SCAN_N + SCAN_CH - 1) / SCAN_CH)  // 196

typedef __attribute__((ext_vector_type(8))) _Float16 half8;
typedef __attribute__((ext_vector_type(8))) short short8;
typedef __attribute__((ext_vector_type(4))) float f32x4;

__device__ __forceinline__ unsigned short f2h(float f) {
    _Float16 h = (_Float16)f;                       // v_cvt_f16_f32, RNE
    return __builtin_bit_cast(unsigned short, h);
}
__device__ __forceinline__ float h2f(unsigned short u) {
    return (float)__builtin_bit_cast(_Float16, u);
}

// ---------- preprocessing ----------
__global__ __launch_bounds__(256) void count_kernel(const int* __restrict__ dst,
                                                    const int* __restrict__ typ,
                                                    int* __restrict__ cnt, int E) {
    int e = blockIdx.x * 256 + threadIdx.x;
    if (e < E) atomicAdd(&cnt[dst[e] * NR + typ[e]], 1);
}

__global__ __launch_bounds__(256) void inv_kernel(const int* __restrict__ cnt,
                                                  float* __restrict__ inv, int n) {
    int i = blockIdx.x * 256 + threadIdx.x;
    if (i < n) {
        int c = cnt[i];
        inv[i] = 1.0f / (float)(c > 1 ? c : 1);
    }
}

// ---- hierarchical scan
__global__ __launch_bounds__(256) void scan1_kernel(const int* __restrict__ cnt,
                                                    int* __restrict__ loc,
                                                    int* __restrict__ bsum) {
    __shared__ int s[256];
    const int t = threadIdx.x;
    const int base = blockIdx.x * SCAN_CH + t * 8;
    int v[8];
    int sum = 0;
#pragma unroll
    for (int j = 0; j < 8; ++j) {
        int idx = base + j;
        v[j] = (idx < SCAN_N) ? cnt[idx] : 0;
        sum += v[j];
    }
    s[t] = sum;
    __syncthreads();
    for (int off = 1; off < 256; off <<= 1) {
        int u = (t >= off) ? s[t - off] : 0;
        __syncthreads();
        s[t] += u;
        __syncthreads();
    }
    int run = (t == 0) ? 0 : s[t - 1];
#pragma unroll
    for (int j = 0; j < 8; ++j) {
        int idx = base + j;
        if (idx < SCAN_N) loc[idx] = run;
        run += v[j];
    }
    if (t == 255) bsum[blockIdx.x] = s[255];
}

__global__ __launch_bounds__(256) void scan2_kernel(const int* __restrict__ bsum,
                                                    int* __restrict__ boff, int nb) {
    __shared__ int s[256];
    const int t = threadIdx.x;
    s[t] = (t < nb) ? bsum[t] : 0;
    __syncthreads();
    for (int off = 1; off < 256; off <<= 1) {
        int u = (t >= off) ? s[t - off] : 0;
        __syncthreads();
        s[t] += u;
        __syncthreads();
    }
    if (t < nb) boff[t] = (t == 0) ? 0 : s[t - 1];
    if (t == nb - 1) boff[nb] = s[t];
}

__global__ __launch_bounds__(256) void scan3_kernel(int* __restrict__ rowptr,
                                                    int* __restrict__ start,
                                                    const int* __restrict__ boff, int nb) {
    const int b = blockIdx.x, t = threadIdx.x;
    const int add = boff[b];
#pragma unroll
    for (int j = 0; j < 8; ++j) {
        int idx = b * SCAN_CH + t * 8 + j;
        if (idx < SCAN_N) {
            int v = rowptr[idx] + add;
            rowptr[idx] = v;
            start[idx] = v;
        }
    }
    if (b == 0 && t == 0) rowptr[SCAN_N] = boff[nb];
}

// counting-sort by (dst,rel): srcrel[pos] = src | rel<<20
__global__ __launch_bounds__(256) void fill_kernel(const int* __restrict__ src,
                                                   const int* __restrict__ dst,
                                                   const int* __restrict__ typ,
                                                   int* __restrict__ start,
                                                   int* __restrict__ srcrel, int E) {
    int e = blockIdx.x * 256 + threadIdx.x;
    if (e >= E) return;
    int r = typ[e];
    int pos = atomicAdd(&start[dst[e] * NR + r], 1);
    srcrel[pos] = src[e] | (r << 20);
}

// ---------- x (fp32, [NN,128]) -> xh (fp16) ----------
__global__ __launch_bounds__(256) void cvt_kernel(const float* __restrict__ x,
                                                  unsigned short* __restrict__ xh, int n4) {
    int i = blockIdx.x * 256 + threadIdx.x;
    if (i >= n4) return;
    float4 v = ((const float4*)x)[i];
    uint2 u;
    u.x = (unsigned)f2h(v.x) | ((unsigned)f2h(v.y) << 16);
    u.y = (unsigned)f2h(v.z) | ((unsigned)f2h(v.w) << 16);
    ((uint2*)xh)[i] = u;
}

// ---------- weight pack: Bt[n][k] fp16, n in [0,9*O): n<8*O -> W[r=n/O][k][o=n%O], else root[k][n-8*O]
__global__ __launch_bounds__(256) void pack_b_kernel(const float* __restrict__ W,
                                                     const float* __restrict__ root,
                                                     unsigned short* __restrict__ Bt, int O) {
    int i = blockIdx.x * 256 + threadIdx.x;
    int NTOT = 9 * O;
    if (i >= NTOT * 128) return;
    int k = i & 127, n = i >> 7;
    float v = (n < 8 * O) ? W[(size_t)(n / O) * 128 * O + (size_t)k * O + (n % O)]
                          : root[(size_t)k * O + (n - 8 * O)];
    Bt[(size_t)n * 128 + k] = f2h(v);
}

// ---------- fused aggregate-first RGCN layer ----------
// h[dst] = sum_r (mean_{src in N_r(dst)} X[src]) @ W_r + X[dst] @ root + b  (+ sigmoid)
// Block: 16 dst, 8 waves (512 thr), ~36 KB LDS.
// Phase 1: waves CLAIM dst dynamically (LDS atomic) for load balance; per dst,
// 16-deep gather bursts (all loads issued before any consume) into NAMED
// per-relation accumulators; fp16-pack to XOR-swizzled LDS row.
// Phase 2: 16xO GEMM, K=9*128 (root streamed from global), MFMA 16x16x32 f16.
#define ACC_EDGE(P, G)                                                        \
    do {                                                                      \
        unsigned r_ = ((unsigned)(P)) >> 20;                                  \
        float vx_ = h2f((unsigned short)((G) & 0xFFFFu));                     \
        float vy_ = h2f((unsigned short)((G) >> 16));                         \
        switch (r_) {                                                         \
            case 0: a0x += vx_; a0y += vy_; break;                            \
            case 1: a1x += vx_; a1y += vy_; break;                            \
            case 2: a2x += vx_; a2y += vy_; break;                            \
            case 3: a3x += vx_; a3y += vy_; break;                            \
            case 4: a4x += vx_; a4y += vy_; break;                            \
            case 5: a5x += vx_; a5y += vy_; break;                            \
            case 6: a6x += vx_; a6y += vy_; break;                            \
            default: a7x += vx_; a7y += vy_; break;                           \
        }                                                                     \
    } while (0)

#define G1(k)                                                                 \
    int p##k = __builtin_amdgcn_readlane(pv, j + k);                          \
    unsigned g##k = X2[(size_t)(p##k & 0xFFFFF) * 64 + lane];

#define A1(k) ACC_EDGE(p##k, g##k)

#define STORE_ROW(R, AX, AY)                                                  \
    do {                                                                      \
        unsigned u_ = (unsigned)f2h((AX) * iv##R) |                           \
                      ((unsigned)f2h((AY) * iv##R) << 16);                    \
        *(unsigned*)(rowp + (((R)*256 + lane * 4) ^ swz)) = u_;               \
    } while (0)

template <int O, bool FINAL>
__global__ __launch_bounds__(512, 6) void fused_layer(
    const int* __restrict__ rp, const int* __restrict__ srcrel,
    const float* __restrict__ inv, const unsigned short* __restrict__ X,
    const unsigned short* __restrict__ Bt, const float* __restrict__ bias,
    void* __restrict__ Hout) {
    __shared__ __align__(16) unsigned short As[16 * 1024];      // 32 KB
    __shared__ float pbuf[FINAL ? 4 * 16 * 16 : 4];             // 4 KB (O=64 only)
    __shared__ int claim_ctr;
    const int t = threadIdx.x;
    const int w = t >> 6, lane = t & 63;
    const int bm = blockIdx.x * 16;                              // 50000 % 16 == 0
    const unsigned* X2 = (const unsigned*)X;  // half2 view, row stride 64

    if (t == 0) claim_ctr = 0;
    __syncthreads();

    // ---- phase 1: dynamic claiming, one dst at a time per wave ----
    for (;;) {
        int c = 0;
        if (lane == 0) c = atomicAdd(&claim_ctr, 1);
        c = __builtin_amdgcn_readfirstlane(c);
        if (c >= 16) break;
        const int m = c;
        const int d = bm + m;

        float a0x = 0.f, a0y = 0.f, a1x = 0.f, a1y = 0.f;
        float a2x = 0.f, a2y = 0.f, a3x = 0.f, a3y = 0.f;
        float a4x = 0.f, a4y = 0.f, a5x = 0.f, a5y = 0.f;
        float a6x = 0.f, a6y = 0.f, a7x = 0.f, a7y = 0.f;

        // preload per-(dst,rel) inverse counts (off the flush critical path)
        const float iv0 = inv[d * 8 + 0], iv1 = inv[d * 8 + 1];
        const float iv2 = inv[d * 8 + 2], iv3 = inv[d * 8 + 3];
        const float iv4 = inv[d * 8 + 4], iv5 = inv[d * 8 + 5];
        const float iv6 = inv[d * 8 + 6], iv7 = inv[d * 8 + 7];

        const int beg = rp[d * 8], end = rp[d * 8 + 8];
        for (int base = beg; base < end; base += 64) {
            int nv = end - base;
            nv = nv > 64 ? 64 : nv;
            int idx = base + (lane < nv ? lane : nv - 1);
            int pv = srcrel[idx];  // batched edge records, one per lane
            int j = 0;
            for (; j + 15 < nv; j += 16) {   // 16 gathers in flight
                G1(0) G1(1) G1(2) G1(3) G1(4) G1(5) G1(6) G1(7)
                G1(8) G1(9) G1(10) G1(11) G1(12) G1(13) G1(14) G1(15)
                A1(0); A1(1); A1(2); A1(3); A1(4); A1(5); A1(6); A1(7);
                A1(8); A1(9); A1(10); A1(11); A1(12); A1(13); A1(14); A1(15);
            }
            if (j + 7 < nv) {
                G1(0) G1(1) G1(2) G1(3) G1(4) G1(5) G1(6) G1(7)
                A1(0); A1(1); A1(2); A1(3); A1(4); A1(5); A1(6); A1(7);
                j += 8;
            }
            if (j + 3 < nv) {
                G1(0) G1(1) G1(2) G1(3)
                A1(0); A1(1); A1(2); A1(3);
                j += 4;
            }
            for (; j < nv; ++j) {
                int p0 = __builtin_amdgcn_readlane(pv, j);
                unsigned g0 = X2[(size_t)(p0 & 0xFFFFF) * 64 + lane];
                ACC_EDGE(p0, g0);
            }
        }
        // scale by 1/cnt, fp16-pack, swizzled LDS store (conflict-free)
        char* rowp = (char*)As + m * 2048;
        const int swz = (m & 7) << 4;
        STORE_ROW(0, a0x, a0y);
        STORE_ROW(1, a1x, a1y);
        STORE_ROW(2, a2x, a2y);
        STORE_ROW(3, a3x, a3y);
        STORE_ROW(4, a4x, a4y);
        STORE_ROW(5, a5x, a5y);
        STORE_ROW(6, a6x, a6y);
        STORE_ROW(7, a7x, a7y);
    }
    __syncthreads();

    // ---- phase 2: [16 x 9*128] @ Bt^T -> [16 x O] ----
    const int q = lane >> 4, ml = lane & 15;
    int col, ksb;
    if (O == 128) {            // 8 waves x one 16-col tile, full K (36 ksteps)
        col = w * 16;
        ksb = 0;
    } else {                   // 4 col tiles x 2 K-groups of 18 ksteps
        col = (w & 3) * 16;
        ksb = (w >> 2) * 18;
    }
    constexpr int NKS = (O == 128) ? 36 : 18;

    f32x4 acc0 = (f32x4)0.f, acc1 = (f32x4)0.f;
    const unsigned short* Xroot = X + (size_t)(bm + ml) * 128;
    const char* arowp = (const char*)As + ml * 2048;
    const int aswz = (ml & 7) << 4;

#pragma unroll 6
    for (int u = 0; u < NKS; ++u) {
        int ks = ksb + u;
        int r = ks >> 2, kk = ks & 3;
        half8 af;
        if (r < 8) {
            af = __builtin_bit_cast(
                half8,
                *(const short8*)(arowp + ((r * 256 + kk * 64 + q * 16) ^ aswz)));
        } else {
            af = __builtin_bit_cast(half8,
                                    *(const short8*)(Xroot + kk * 32 + q * 8));
        }
        half8 bf = __builtin_bit_cast(
            half8,
            *(const short8*)(Bt + (size_t)(r * O + col + ml) * 128 + kk * 32 +
                             q * 8));
        if (u & 1)
            acc1 = __builtin_amdgcn_mfma_f32_16x16x32_f16(af, bf, acc1, 0, 0, 0);
        else
            acc0 = __builtin_amdgcn_mfma_f32_16x16x32_f16(af, bf, acc0, 0, 0, 0);
    }
    f32x4 accv = acc0 + acc1;

    // epilogue: C/D layout col=lane&15, row=q*4+j
    if (!FINAL) {
        float bv = bias[col + ml];
#pragma unroll
        for (int j = 0; j < 4; ++j) {
            int grow = bm + q * 4 + j;
            ((unsigned short*)Hout)[(size_t)grow * O + col + ml] =
                f2h(accv[j] + bv);
        }
    } else {
        const int kg = w >> 2, ci = w & 3;
        if (kg == 1) {
#pragma unroll
            for (int j = 0; j < 4; ++j)
                pbuf[ci * 256 + (q * 4 + j) * 16 + ml] = accv[j];
        }
        __syncthreads();
        if (kg == 0) {
            float bv = bias[col + ml];
#pragma unroll
            for (int j = 0; j < 4; ++j) {
                int grow = bm + q * 4 + j;
                float v = accv[j] + pbuf[ci * 256 + (q * 4 + j) * 16 + ml] + bv;
                ((float*)Hout)[(size_t)grow * O + col + ml] =
                    1.f / (1.f + __expf(-v));
            }
        }
    }
}

extern "C" void kernel_launch(void* const* d_in, const int* in_sizes, int n_in,
                              void* d_out, int out_size, void* d_ws, size_t ws_size,
                              hipStream_t stream) {
    const float* x     = (const float*)d_in[0];
    const int*   esrc  = (const int*)d_in[1];
    const int*   edst  = (const int*)d_in[2];
    const int*   etyp  = (const int*)d_in[3];
    const float* W1    = (const float*)d_in[4];
    const float* root1 = (const float*)d_in[5];
    const float* b1    = (const float*)d_in[6];
    const float* W2    = (const float*)d_in[7];
    const float* root2 = (const float*)d_in[8];
    const float* b2    = (const float*)d_in[9];
    float* out = (float*)d_out;

    char* ws = (char*)d_ws;
    unsigned short* Bt1    = (unsigned short*)ws; ws += (size_t)1152 * 128 * 2; // 288 KB
    unsigned short* Bt2    = (unsigned short*)ws; ws += (size_t)576 * 128 * 2;  // 144 KB
    int*            cnt    = (int*)ws;            ws += (size_t)SCAN_N * 4;     // 1.6 MB
    float*          inv    = (float*)ws;          ws += (size_t)SCAN_N * 4;     // 1.6 MB
    int*            rp     = (int*)ws;            ws += (size_t)(SCAN_N + 64) * 4;
    int*            start  = (int*)ws;            ws += (size_t)SCAN_N * 4;     // 1.6 MB
    int*            bsum   = (int*)ws;            ws += (size_t)256 * 4;
    int*            boff   = (int*)ws;            ws += (size_t)257 * 4;
    int*            srcrel = (int*)ws;            ws += (size_t)NE * 4;         // 2.56 MB
    unsigned short* xh     = (unsigned short*)ws; ws += (size_t)NN * 128 * 2;   // 12.8 MB
    unsigned short* h1b    = (unsigned short*)ws;                               // 12.8 MB

    // CSR by (dst, rel) — hierarchical scan, fully parallel
    hipMemsetAsync(cnt, 0, (size_t)SCAN_N * 4, stream);
    count_kernel<<<(NE + 255) / 256, 256, 0, stream>>>(edst, etyp, cnt, NE);
    inv_kernel<<<(SCAN_N + 255) / 256, 256, 0, stream>>>(cnt, inv, SCAN_N);
    scan1_kernel<<<SCAN_NB, 256, 0, stream>>>(cnt, rp, bsum);
    scan2_kernel<<<1, 256, 0, stream>>>(bsum, boff, SCAN_NB);
    scan3_kernel<<<SCAN_NB, 256, 0, stream>>>(rp, start, boff, SCAN_NB);
    fill_kernel<<<(NE + 255) / 256, 256, 0, stream>>>(esrc, edst, etyp, start, srcrel, NE);

    // fp16 conversions / packs
    cvt_kernel<<<(NN * 32 + 255) / 256, 256, 0, stream>>>(x, xh, NN * 32);
    pack_b_kernel<<<(1152 * 128 + 255) / 256, 256, 0, stream>>>(W1, root1, Bt1, 128);
    pack_b_kernel<<<(576 * 128 + 255) / 256, 256, 0, stream>>>(W2, root2, Bt2, 64);

    const int fgrid = NN / 16;  // 3125 blocks of 16 dst, 512 threads

    // layer 1: aggregate-first fused (mean_r(x) @ W_r + x @ root1 + b1) -> h1b fp16
    fused_layer<128, false><<<fgrid, 512, 0, stream>>>(rp, srcrel, inv, xh, Bt1, b1, h1b);
    // layer 2: same on h1b, + sigmoid -> out fp32
    fused_layer<64, true><<<fgrid, 512, 0, stream>>>(rp, srcrel, inv, h1b, Bt2, b2, out);
}